// Round 14
// baseline (223.911 us; speedup 1.0000x reference)
//
#include <hip/hip_runtime.h>

#define NN 100000
#define EE 1600000
#define FF 64

#define NBKT 391          // ceil(NN/256) coarse buckets (col>>8)
#define BKW 256           // nodes per bucket
#define CAP 8192          // record capacity per bucket
#define EPB 6250          // edges per pass-1 block (EE/256 exactly)
#define P2CAP 6144        // LDS staging capacity in pass 2 (48 KB)

#define FIX 68719476736.0f       // 2^36
#define FIXINV (1.0/68719476736.0)

typedef unsigned long long ull;
typedef __attribute__((ext_vector_type(8))) short bf16x8;   // 8 bf16 (4 VGPRs)
typedef __attribute__((ext_vector_type(4))) float f32x4;    // MFMA acc
typedef __attribute__((ext_vector_type(2))) float f32x2;

__device__ inline unsigned pack_bf16x2(float a, float b) {
    unsigned ua = __float_as_uint(a), ub = __float_as_uint(b);
    ua = (ua + 0x7FFFu + ((ua >> 16) & 1u)) >> 16;
    ub = (ub + 0x7FFFu + ((ub >> 16) & 1u)) >> 16;
    return ua | (ub << 16);
}
__device__ inline float bf_lo(unsigned u) { return __uint_as_float(u << 16); }
__device__ inline float bf_hi(unsigned u) { return __uint_as_float(u & 0xFFFF0000u); }
__device__ inline short bf16_of(float f) {
    unsigned u = __float_as_uint(f);
    u = (u + 0x7FFFu + ((u >> 16) & 1u)) >> 16;
    return (short)u;
}
// pack two f32 -> two fp8 e4m3 bytes (HW convert)
__device__ inline unsigned short fp8x2_of(float a, float b) {
    int p = __builtin_amdgcn_cvt_pk_fp8_f32(a, b, 0, false);
    return (unsigned short)(p & 0xFFFF);
}

// B-frag: lane holds W[c*32 + kg*8 + i][col], i=0..7 (K=32 chunk c)
__device__ inline bf16x8 load_bfrag(const float* __restrict__ W, int col, int kg, int c) {
    bf16x8 f;
    #pragma unroll
    for (int i = 0; i < 8; ++i)
        f[i] = bf16_of(W[(c*32 + kg*8 + i)*FF + col]);
    return f;
}
// A-frags (2 K-chunks) for one x row pointer
__device__ inline void load_afrag(const float* __restrict__ xp, bf16x8& A0, bf16x8& A1) {
    float4 v0 = *(const float4*)xp;
    float4 v1 = *(const float4*)(xp + 4);
    float4 v2 = *(const float4*)(xp + 32);
    float4 v3 = *(const float4*)(xp + 36);
    A0[0]=bf16_of(v0.x); A0[1]=bf16_of(v0.y); A0[2]=bf16_of(v0.z); A0[3]=bf16_of(v0.w);
    A0[4]=bf16_of(v1.x); A0[5]=bf16_of(v1.y); A0[6]=bf16_of(v1.z); A0[7]=bf16_of(v1.w);
    A1[0]=bf16_of(v2.x); A1[1]=bf16_of(v2.y); A1[2]=bf16_of(v2.z); A1[3]=bf16_of(v2.w);
    A1[4]=bf16_of(v3.x); A1[5]=bf16_of(v3.y); A1[6]=bf16_of(v3.z); A1[7]=bf16_of(v3.w);
}

// ==== Pass 1: LDS counting sort by col>>8, coalesced run writes (512 thr) ====
__global__ __launch_bounds__(512) void k_p1(const int* __restrict__ row,
                                            const int* __restrict__ col,
                                            const float* __restrict__ ew,
                                            int* __restrict__ gcnt,
                                            uint2* __restrict__ records) {
    __shared__ uint2 srt[EPB];        // 50 KB sorted records
    __shared__ int colsS[EPB];        // 25 KB staged cols
    __shared__ int histo[NBKT];
    __shared__ int lbase[NBKT];
    __shared__ int gbase[NBKT];
    __shared__ int cur[NBKT];
    __shared__ int tmp[512];
    int tid = threadIdx.x;
    for (int i = tid; i < NBKT; i += 512) histo[i] = 0;
    __syncthreads();
    int s0 = blockIdx.x * EPB;
    #pragma unroll 1
    for (int r = 0; r < 13; ++r) {
        int t = r*512 + tid;
        if (t < EPB) {
            int c = col[s0 + t];
            colsS[t] = c;
            atomicAdd(&histo[c >> 8], 1);
        }
    }
    __syncthreads();
    int v = (tid < NBKT) ? histo[tid] : 0;
    tmp[tid] = v;
    __syncthreads();
    #pragma unroll
    for (int s = 1; s < 512; s <<= 1) {
        int t = (tid >= s) ? tmp[tid - s] : 0;
        __syncthreads();
        tmp[tid] += t;
        __syncthreads();
    }
    if (tid < NBKT) {
        int ex = tmp[tid] - v;
        lbase[tid] = ex;
        cur[tid] = ex;
        gbase[tid] = atomicAdd(&gcnt[tid], v);
    }
    __syncthreads();
    #pragma unroll 1
    for (int r = 0; r < 13; ++r) {
        int t = r*512 + tid;
        if (t < EPB) {
            int i = s0 + t;
            int c = colsS[t];
            int b = c >> 8;
            int slot = atomicAdd(&cur[b], 1);
            srt[slot] = make_uint2(((unsigned)row[i] << 8) | (unsigned)(c & 255),
                                   __float_as_uint(ew[i]));
        }
    }
    __syncthreads();
    int wid = tid >> 6, lane = tid & 63;
    for (int b = wid; b < NBKT; b += 8) {
        int n = histo[b], lb = lbase[b];
        size_t gb = (size_t)b*CAP + gbase[b];
        for (int i = lane; i < n; i += 64) records[gb + i] = srt[lb + i];
    }
}

// ==== Pass 2: u64 LDS hist+deg, scan, ranked 8B-edat write (512 thr) ====
__global__ __launch_bounds__(512) void k_p2(const int* __restrict__ gcnt,
                                            const uint2* __restrict__ records,
                                            int* __restrict__ off,
                                            float* __restrict__ dinv,
                                            uint2* __restrict__ edat) {
    __shared__ uint2 rstage[P2CAP];   // 48 KB
    __shared__ ull hd[BKW];           // [cnt:16 | deg Q36:48]
    __shared__ int cur[BKW];
    __shared__ int tmp[512];
    int tid = threadIdx.x;
    int b = blockIdx.x;
    int cnt = gcnt[b];
    // fused exclusive scan of bucket totals -> obase
    int v = (tid < NBKT) ? gcnt[tid] : 0;
    tmp[tid] = v;
    __syncthreads();
    #pragma unroll
    for (int s = 1; s < 512; s <<= 1) {
        int t = (tid >= s) ? tmp[tid - s] : 0;
        __syncthreads();
        tmp[tid] += t;
        __syncthreads();
    }
    int obase = tmp[b] - cnt;
    if (b == 0 && tid == 0) off[NN] = EE;
    if (tid < BKW) hd[tid] = 0ull;
    __syncthreads();
    size_t rbase = (size_t)b * CAP;
    for (int j = tid; j < cnt; j += 512) {
        uint2 rec = records[rbase + j];
        if (j < P2CAP) rstage[j] = rec;
        int c8 = rec.x & 255;
        atomicAdd(&hd[c8], (1ull << 48) | (ull)(__uint_as_float(rec.y) * FIX));
    }
    __syncthreads();
    int hv = (tid < BKW) ? (int)(hd[tid] >> 48) : 0;
    tmp[tid] = hv;
    __syncthreads();
    #pragma unroll
    for (int s = 1; s < 512; s <<= 1) {
        int t = (tid >= s) ? tmp[tid - s] : 0;
        __syncthreads();
        tmp[tid] += t;
        __syncthreads();
    }
    if (tid < BKW) {
        int excl = tmp[tid] - hv;
        cur[tid] = excl;
        int node = b*BKW + tid;
        if (node < NN) {
            off[node] = obase + excl;
            float d = (float)((double)(hd[tid] & 0xFFFFFFFFFFFFull) * FIXINV);
            dinv[node] = d > 0.f ? rsqrtf(fmaxf(d, 1e-12f)) : 0.f;
        }
    }
    __syncthreads();
    for (int j = tid; j < cnt; j += 512) {
        uint2 rec = (j < P2CAP) ? rstage[j] : records[rbase + j];
        int c8 = rec.x & 255;
        int slot = atomicAdd(&cur[c8], 1);
        // {u16-element base of src row, weight as raw f32} — zero unpack in pull
        edat[obase + slot] = make_uint2((rec.x >> 8) << 6, rec.y);
    }
}

// ==== hbf8 projection: hbf8 = fp8(x@iw_k0, x@iw_k1) * dinv ====
__global__ __launch_bounds__(256) void k_projh(const float* __restrict__ x,
                                               const float* __restrict__ iw,
                                               const float* __restrict__ dsc,
                                               unsigned short* __restrict__ hbf8) {
    int lane = threadIdx.x & 63, wid = threadIdx.x >> 6;
    int col16 = lane & 15, kg = lane >> 4;
    int col = wid*16 + col16;

    bf16x8 Bi[2][2];
    #pragma unroll
    for (int k = 0; k < 2; ++k)
        #pragma unroll
        for (int c = 0; c < 2; ++c)
            Bi[k][c] = load_bfrag(iw + k*4096, col, kg, c);

    int base = blockIdx.x * 64;
    #pragma unroll
    for (int s = 0; s < 4; ++s) {
        int arow = base + s*16 + col16;
        if (arow >= NN) arow = NN - 1;
        bf16x8 A0, A1;
        load_afrag(x + arow*FF + kg*8, A0, A1);

        f32x4 h0 = {0.f,0.f,0.f,0.f}, h1 = {0.f,0.f,0.f,0.f};
        h0 = __builtin_amdgcn_mfma_f32_16x16x32_bf16(A0, Bi[0][0], h0, 0, 0, 0);
        h0 = __builtin_amdgcn_mfma_f32_16x16x32_bf16(A1, Bi[0][1], h0, 0, 0, 0);
        h1 = __builtin_amdgcn_mfma_f32_16x16x32_bf16(A0, Bi[1][0], h1, 0, 0, 0);
        h1 = __builtin_amdgcn_mfma_f32_16x16x32_bf16(A1, Bi[1][1], h1, 0, 0, 0);
        #pragma unroll
        for (int r = 0; r < 4; ++r) {
            int node = base + s*16 + kg*4 + r;
            if (node < NN) {
                float f = dsc[node];
                hbf8[(node<<6) + col] = fp8x2_of(h0[r]*f, h1[r]*f);
            }
        }
    }
}

// ==== MFMA layer matmul: outp8 = fp8(in_k0@W[0], in_k1@W[1]) * dinv ====
__global__ __launch_bounds__(256) void k_mml(const unsigned* __restrict__ in,
                                             const float* __restrict__ W,
                                             const float* __restrict__ dsc,
                                             unsigned short* __restrict__ outp8) {
    int lane = threadIdx.x & 63, wid = threadIdx.x >> 6;
    int col16 = lane & 15, kg = lane >> 4;
    int col = wid*16 + col16;

    bf16x8 B0[2], B1[2];
    #pragma unroll
    for (int c = 0; c < 2; ++c) {
        B0[c] = load_bfrag(W, col, kg, c);
        B1[c] = load_bfrag(W + 4096, col, kg, c);
    }
    int base = blockIdx.x * 64;
    #pragma unroll
    for (int s = 0; s < 4; ++s) {
        int arow = base + s*16 + col16;
        if (arow >= NN) arow = NN - 1;
        const unsigned* ip = in + arow*FF + kg*8;
        uint4 u0 = *(const uint4*)ip;
        uint4 u1 = *(const uint4*)(ip + 4);
        uint4 u2 = *(const uint4*)(ip + 32);
        uint4 u3 = *(const uint4*)(ip + 36);
        unsigned uu[16] = {u0.x,u0.y,u0.z,u0.w, u1.x,u1.y,u1.z,u1.w,
                           u2.x,u2.y,u2.z,u2.w, u3.x,u3.y,u3.z,u3.w};
        bf16x8 A00, A01, A10, A11;
        #pragma unroll
        for (int i = 0; i < 8; ++i) {
            A00[i] = (short)(uu[i] & 0xFFFFu);      A10[i] = (short)(uu[i] >> 16);
            A01[i] = (short)(uu[8+i] & 0xFFFFu);    A11[i] = (short)(uu[8+i] >> 16);
        }
        f32x4 a0 = {0.f, 0.f, 0.f, 0.f};
        f32x4 a1 = {0.f, 0.f, 0.f, 0.f};
        a0 = __builtin_amdgcn_mfma_f32_16x16x32_bf16(A00, B0[0], a0, 0, 0, 0);
        a0 = __builtin_amdgcn_mfma_f32_16x16x32_bf16(A01, B0[1], a0, 0, 0, 0);
        a1 = __builtin_amdgcn_mfma_f32_16x16x32_bf16(A10, B1[0], a1, 0, 0, 0);
        a1 = __builtin_amdgcn_mfma_f32_16x16x32_bf16(A11, B1[1], a1, 0, 0, 0);
        #pragma unroll
        for (int r = 0; r < 4; ++r) {
            int node = base + s*16 + kg*4 + r;
            if (node < NN) {
                float f = dsc[node];
                outp8[(node<<6) + col] = fp8x2_of(a0[r]*f, a1[r]*f);
            }
        }
    }
}

// ==== pull: in-kernel MFMA root + 2 nodes/wave gather (8B edat, fp8 payload) ====
__global__ __launch_bounds__(512) void k_pull(const int* __restrict__ off,
                                              const uint2* __restrict__ edat,
                                              const unsigned short* __restrict__ hbf,
                                              const float* __restrict__ x,
                                              const float* __restrict__ rw,
                                              const float* __restrict__ bias,
                                              const float* __restrict__ dinv,
                                              unsigned* __restrict__ out_bf,
                                              float* __restrict__ out_f32,
                                              int final_mean) {
    __shared__ float rootf[2][16][FF];   // 8 KB: root+bias for block's 16 nodes
    __shared__ uint2 ech[8][64];         // 4 KB: per-wave edge chunks
    int tid = threadIdx.x;
    int lane = tid & 63;
    int sub = tid >> 6;
    int nbase = blockIdx.x * 16;         // 6250 blocks * 16 nodes == NN

    // ---- producer phase: 8 waves = (4 col-tiles x 2 k); 2 MFMAs each ----
    {
        int ct = sub & 3, kk = sub >> 2;
        int col16 = lane & 15, kg = lane >> 4;
        int c = ct*16 + col16;
        bf16x8 Bc0 = load_bfrag(rw + kk*4096, c, kg, 0);
        bf16x8 Bc1 = load_bfrag(rw + kk*4096, c, kg, 1);
        bf16x8 A0, A1;
        load_afrag(x + (nbase + col16)*FF + kg*8, A0, A1);
        float bv = bias[kk*FF + c];
        f32x4 acc = {bv, bv, bv, bv};
        acc = __builtin_amdgcn_mfma_f32_16x16x32_bf16(A0, Bc0, acc, 0, 0, 0);
        acc = __builtin_amdgcn_mfma_f32_16x16x32_bf16(A1, Bc1, acc, 0, 0, 0);
        #pragma unroll
        for (int r = 0; r < 4; ++r)
            rootf[kk][kg*4 + r][c] = acc[r];
    }
    __syncthreads();

    // ---- consumer phase: wave sub owns nodes nbase+2*sub, +1 ----
    int n0 = nbase + sub*2, n1 = n0 + 1;
    float r00 = rootf[0][sub*2][lane],     r01 = rootf[1][sub*2][lane];
    float r10 = rootf[0][sub*2 + 1][lane], r11 = rootf[1][sub*2 + 1][lane];
    float dc0 = dinv[n0], dc1 = dinv[n1];
    int beg = off[n0], mid = off[n0+1], end = off[n0+2];

    float pa0=0.f,pa1=0.f,pb0=0.f,pb1=0.f,pc0=0.f,pc1=0.f,pd0=0.f,pd1=0.f;
    float qa0=0.f,qa1=0.f,qb0=0.f,qb1=0.f,qc0=0.f,qc1=0.f,qd0=0.f,qd1=0.f;

    for (int base = beg; base < end; base += 64) {
        int rem = end - base;
        int cc = rem < 64 ? rem : 64;
        ech[sub][lane] = (lane < cc) ? edat[base + lane] : make_uint2(0u, 0u);
        __builtin_amdgcn_wave_barrier();
        int midrel = mid - base;
        if (midrel < 0) midrel = 0;
        if (midrel > 64) midrel = 64;
        int padded = (cc + 7) & ~7;
        for (int q = 0; q < padded; q += 8) {
            uint2 e[8];
            #pragma unroll
            for (int i = 0; i < 8; ++i) e[i] = ech[sub][q + i];
            unsigned us[8];
            #pragma unroll
            for (int i = 0; i < 8; ++i) us[i] = hbf[e[i].x + lane];
            if (q + 8 <= midrel) {
                #pragma unroll
                for (int i = 0; i < 8; ++i) {
                    float w = __uint_as_float(e[i].y);
                    f32x2 h = __builtin_amdgcn_cvt_pk_f32_fp8(us[i], false);
                    if      ((i & 3) == 0) { pa0 = fmaf(w, h.x, pa0); pa1 = fmaf(w, h.y, pa1); }
                    else if ((i & 3) == 1) { pb0 = fmaf(w, h.x, pb0); pb1 = fmaf(w, h.y, pb1); }
                    else if ((i & 3) == 2) { pc0 = fmaf(w, h.x, pc0); pc1 = fmaf(w, h.y, pc1); }
                    else                   { pd0 = fmaf(w, h.x, pd0); pd1 = fmaf(w, h.y, pd1); }
                }
            } else if (q >= midrel) {
                #pragma unroll
                for (int i = 0; i < 8; ++i) {
                    float w = __uint_as_float(e[i].y);
                    f32x2 h = __builtin_amdgcn_cvt_pk_f32_fp8(us[i], false);
                    if      ((i & 3) == 0) { qa0 = fmaf(w, h.x, qa0); qa1 = fmaf(w, h.y, qa1); }
                    else if ((i & 3) == 1) { qb0 = fmaf(w, h.x, qb0); qb1 = fmaf(w, h.y, qb1); }
                    else if ((i & 3) == 2) { qc0 = fmaf(w, h.x, qc0); qc1 = fmaf(w, h.y, qc1); }
                    else                   { qd0 = fmaf(w, h.x, qd0); qd1 = fmaf(w, h.y, qd1); }
                }
            } else {
                #pragma unroll
                for (int i = 0; i < 8; ++i) {
                    float w = __uint_as_float(e[i].y);
                    f32x2 h = __builtin_amdgcn_cvt_pk_f32_fp8(us[i], false);
                    if (q + i < midrel) {
                        if      ((i & 3) == 0) { pa0 = fmaf(w, h.x, pa0); pa1 = fmaf(w, h.y, pa1); }
                        else if ((i & 3) == 1) { pb0 = fmaf(w, h.x, pb0); pb1 = fmaf(w, h.y, pb1); }
                        else if ((i & 3) == 2) { pc0 = fmaf(w, h.x, pc0); pc1 = fmaf(w, h.y, pc1); }
                        else                   { pd0 = fmaf(w, h.x, pd0); pd1 = fmaf(w, h.y, pd1); }
                    } else {
                        if      ((i & 3) == 0) { qa0 = fmaf(w, h.x, qa0); qa1 = fmaf(w, h.y, qa1); }
                        else if ((i & 3) == 1) { qb0 = fmaf(w, h.x, qb0); qb1 = fmaf(w, h.y, qb1); }
                        else if ((i & 3) == 2) { qc0 = fmaf(w, h.x, qc0); qc1 = fmaf(w, h.y, qc1); }
                        else                   { qd0 = fmaf(w, h.x, qd0); qd1 = fmaf(w, h.y, qd1); }
                    }
                }
            }
        }
        __builtin_amdgcn_wave_barrier();
    }
    float s00 = fmaxf(fmaf(dc0, pa0 + pb0 + pc0 + pd0, r00), 0.f);
    float s01 = fmaxf(fmaf(dc0, pa1 + pb1 + pc1 + pd1, r01), 0.f);
    float s10 = fmaxf(fmaf(dc1, qa0 + qb0 + qc0 + qd0, r10), 0.f);
    float s11 = fmaxf(fmaf(dc1, qa1 + qb1 + qc1 + qd1, r11), 0.f);
    if (final_mean) {
        out_f32[n0*FF + lane] = 0.5f * (s00 + s01);
        out_f32[n1*FF + lane] = 0.5f * (s10 + s11);
    } else {
        out_bf[(n0<<6) + lane] = pack_bf16x2(s00, s01);
        out_bf[(n1<<6) + lane] = pack_bf16x2(s10, s11);
    }
}

extern "C" void kernel_launch(void* const* d_in, const int* in_sizes, int n_in,
                              void* d_out, int out_size, void* d_ws, size_t ws_size,
                              hipStream_t stream) {
    const float* x    = (const float*)d_in[0];
    const int*   ei   = (const int*)d_in[1];
    const float* ew   = (const float*)d_in[2];
    const float* iw   = (const float*)d_in[3];   // [K,64,64]
    const float* w    = (const float*)d_in[4];   // [T-1,K,64,64]
    const float* rw   = (const float*)d_in[5];   // [T,K,64,64]
    const float* bias = (const float*)d_in[6];   // [T,K,64]
    float* out = (float*)d_out;

    // workspace layout (~77 MB)
    uint2* records = (uint2*)d_ws;                        // NBKT*CAP*8B = 25.6 MB
    unsigned short* hbf8 = (unsigned short*)(records + (size_t)NBKT*CAP);  // NN*64*2B
    unsigned* gbf  = (unsigned*)(hbf8 + (NN<<6));         // NN*64*4B
    uint2* edat    = (uint2*)(gbf + (NN<<6));             // EE*8B = 12.8 MB
    float* dinv    = (float*)(edat + EE);                 // NN
    int*   off     = (int*)(dinv + NN);                   // NN+1
    int*   gcnt    = off + NN + 1;                        // NBKT

    const int* row = ei;        // edge_index[0]
    const int* col = ei + EE;   // edge_index[1]

    const int NB = (NN + 63) / 64;   // 1563 MFMA tiles

    // ---- CSR build ----
    hipMemsetAsync(gcnt, 0, NBKT * sizeof(int), stream);
    k_p1<<<256, 512, 0, stream>>>(row, col, ew, gcnt, records);
    k_p2<<<NBKT, 512, 0, stream>>>(gcnt, records, off, dinv, edat);

    // ---- hbf8 projection ----
    k_projh<<<NB, 256, 0, stream>>>(x, iw, dinv, hbf8);

    // ---- t = 0 (root via in-kernel MFMA) ----
    k_pull<<<6250, 512, 0, stream>>>(off, edat, hbf8, x, rw, bias,
                                     dinv, gbf, out, 0);

    // ---- t = 1 ----
    k_mml<<<NB, 256, 0, stream>>>(gbf, w, dinv, hbf8);   // hbf8 = fp8((g@w0)*dinv)
    k_pull<<<6250, 512, 0, stream>>>(off, edat, hbf8, x, rw + 2*4096, bias + 2*FF,
                                     dinv, gbf, out, 1);
}

// Round 15
// 189.852 us; speedup vs baseline: 1.1794x; 1.1794x over previous
//
#include <hip/hip_runtime.h>

#define NN 100000
#define EE 1600000
#define FF 64
#define KK 2

#define NBKT 391          // ceil(NN/256) coarse buckets (col>>8)
#define BKW 256           // nodes per bucket
#define CAP 8192          // record capacity per bucket
#define EPB 6250          // edges per pass-1 block (EE/256 exactly)
#define P2CAP 6144        // LDS staging capacity in pass 2 (48 KB)

#define FIX 68719476736.0f       // 2^36
#define FIXINV (1.0/68719476736.0)

typedef unsigned long long ull;
typedef __attribute__((ext_vector_type(8))) short bf16x8;   // 8 bf16 (4 VGPRs)
typedef __attribute__((ext_vector_type(4))) float f32x4;    // MFMA acc
typedef __attribute__((ext_vector_type(2))) float f32x2;

__device__ inline unsigned pack_bf16x2(float a, float b) {
    unsigned ua = __float_as_uint(a), ub = __float_as_uint(b);
    ua = (ua + 0x7FFFu + ((ua >> 16) & 1u)) >> 16;
    ub = (ub + 0x7FFFu + ((ub >> 16) & 1u)) >> 16;
    return ua | (ub << 16);
}
__device__ inline float bf_lo(unsigned u) { return __uint_as_float(u << 16); }
__device__ inline float bf_hi(unsigned u) { return __uint_as_float(u & 0xFFFF0000u); }
__device__ inline short bf16_of(float f) {
    unsigned u = __float_as_uint(f);
    u = (u + 0x7FFFu + ((u >> 16) & 1u)) >> 16;
    return (short)u;
}
// pack two f32 -> two fp8 e4m3 bytes (HW convert)
__device__ inline unsigned short fp8x2_of(float a, float b) {
    int p = __builtin_amdgcn_cvt_pk_fp8_f32(a, b, 0, false);
    return (unsigned short)(p & 0xFFFF);
}

// B-frag: lane holds W[c*32 + kg*8 + i][col], i=0..7 (K=32 chunk c)
__device__ inline bf16x8 load_bfrag(const float* __restrict__ W, int col, int kg, int c) {
    bf16x8 f;
    #pragma unroll
    for (int i = 0; i < 8; ++i)
        f[i] = bf16_of(W[(c*32 + kg*8 + i)*FF + col]);
    return f;
}

// ==== Pass 1: LDS counting sort by col>>8, coalesced run writes (512 thr) ====
__global__ __launch_bounds__(512) void k_p1(const int* __restrict__ row,
                                            const int* __restrict__ col,
                                            const float* __restrict__ ew,
                                            int* __restrict__ gcnt,
                                            uint2* __restrict__ records) {
    __shared__ uint2 srt[EPB];        // 50 KB sorted records
    __shared__ int colsS[EPB];        // 25 KB staged cols
    __shared__ int histo[NBKT];
    __shared__ int lbase[NBKT];
    __shared__ int gbase[NBKT];
    __shared__ int cur[NBKT];
    __shared__ int tmp[512];
    int tid = threadIdx.x;
    for (int i = tid; i < NBKT; i += 512) histo[i] = 0;
    __syncthreads();
    int s0 = blockIdx.x * EPB;
    #pragma unroll 1
    for (int r = 0; r < 13; ++r) {
        int t = r*512 + tid;
        if (t < EPB) {
            int c = col[s0 + t];
            colsS[t] = c;
            atomicAdd(&histo[c >> 8], 1);
        }
    }
    __syncthreads();
    int v = (tid < NBKT) ? histo[tid] : 0;
    tmp[tid] = v;
    __syncthreads();
    #pragma unroll
    for (int s = 1; s < 512; s <<= 1) {
        int t = (tid >= s) ? tmp[tid - s] : 0;
        __syncthreads();
        tmp[tid] += t;
        __syncthreads();
    }
    if (tid < NBKT) {
        int ex = tmp[tid] - v;
        lbase[tid] = ex;
        cur[tid] = ex;
        gbase[tid] = atomicAdd(&gcnt[tid], v);
    }
    __syncthreads();
    #pragma unroll 1
    for (int r = 0; r < 13; ++r) {
        int t = r*512 + tid;
        if (t < EPB) {
            int i = s0 + t;
            int c = colsS[t];
            int b = c >> 8;
            int slot = atomicAdd(&cur[b], 1);
            srt[slot] = make_uint2(((unsigned)row[i] << 8) | (unsigned)(c & 255),
                                   __float_as_uint(ew[i]));
        }
    }
    __syncthreads();
    int wid = tid >> 6, lane = tid & 63;
    for (int b = wid; b < NBKT; b += 8) {
        int n = histo[b], lb = lbase[b];
        size_t gb = (size_t)b*CAP + gbase[b];
        for (int i = lane; i < n; i += 64) records[gb + i] = srt[lb + i];
    }
}

// ==== Pass 2: u64 LDS hist+deg, scan, ranked 8B-edat write (512 thr) ====
__global__ __launch_bounds__(512) void k_p2(const int* __restrict__ gcnt,
                                            const uint2* __restrict__ records,
                                            int* __restrict__ off,
                                            float* __restrict__ dinv,
                                            uint2* __restrict__ edat) {
    __shared__ uint2 rstage[P2CAP];   // 48 KB
    __shared__ ull hd[BKW];           // [cnt:16 | deg Q36:48]
    __shared__ int cur[BKW];
    __shared__ int tmp[512];
    int tid = threadIdx.x;
    int b = blockIdx.x;
    int cnt = gcnt[b];
    // fused exclusive scan of bucket totals -> obase
    int v = (tid < NBKT) ? gcnt[tid] : 0;
    tmp[tid] = v;
    __syncthreads();
    #pragma unroll
    for (int s = 1; s < 512; s <<= 1) {
        int t = (tid >= s) ? tmp[tid - s] : 0;
        __syncthreads();
        tmp[tid] += t;
        __syncthreads();
    }
    int obase = tmp[b] - cnt;
    if (b == 0 && tid == 0) off[NN] = EE;
    if (tid < BKW) hd[tid] = 0ull;
    __syncthreads();
    size_t rbase = (size_t)b * CAP;
    for (int j = tid; j < cnt; j += 512) {
        uint2 rec = records[rbase + j];
        if (j < P2CAP) rstage[j] = rec;
        int c8 = rec.x & 255;
        atomicAdd(&hd[c8], (1ull << 48) | (ull)(__uint_as_float(rec.y) * FIX));
    }
    __syncthreads();
    int hv = (tid < BKW) ? (int)(hd[tid] >> 48) : 0;
    tmp[tid] = hv;
    __syncthreads();
    #pragma unroll
    for (int s = 1; s < 512; s <<= 1) {
        int t = (tid >= s) ? tmp[tid - s] : 0;
        __syncthreads();
        tmp[tid] += t;
        __syncthreads();
    }
    if (tid < BKW) {
        int excl = tmp[tid] - hv;
        cur[tid] = excl;
        int node = b*BKW + tid;
        if (node < NN) {
            off[node] = obase + excl;
            float d = (float)((double)(hd[tid] & 0xFFFFFFFFFFFFull) * FIXINV);
            dinv[node] = d > 0.f ? rsqrtf(fmaxf(d, 1e-12f)) : 0.f;
        }
    }
    __syncthreads();
    for (int j = tid; j < cnt; j += 512) {
        uint2 rec = (j < P2CAP) ? rstage[j] : records[rbase + j];
        int c8 = rec.x & 255;
        int slot = atomicAdd(&cur[c8], 1);
        // {u16-element base of src row (src<<6), weight as raw f32} — zero unpack in pull
        edat[obase + slot] = make_uint2((rec.x >> 8) << 6, rec.y);
    }
}

// ==== MFMA triple projection (one x pass): hbf8 (fp8), rbf0, rbf1 (bf16) ====
__global__ __launch_bounds__(256) void k_proj3(const float* __restrict__ x,
                                               const float* __restrict__ iw,
                                               const float* __restrict__ rw,
                                               const float* __restrict__ bias,
                                               const float* __restrict__ dsc,
                                               unsigned short* __restrict__ hbf8,
                                               unsigned* __restrict__ rbf0,
                                               unsigned* __restrict__ rbf1) {
    int lane = threadIdx.x & 63, wid = threadIdx.x >> 6;
    int col16 = lane & 15, kg = lane >> 4;
    int col = wid*16 + col16;

    bf16x8 Bi[2][2], B0[2][2], B1[2][2];   // [k][chunk]
    #pragma unroll
    for (int k = 0; k < 2; ++k)
        #pragma unroll
        for (int c = 0; c < 2; ++c) {
            Bi[k][c] = load_bfrag(iw + k*4096, col, kg, c);
            B0[k][c] = load_bfrag(rw + k*4096, col, kg, c);
            B1[k][c] = load_bfrag(rw + (2 + k)*4096, col, kg, c);
        }
    float b00 = bias[col],        b01 = bias[FF + col];
    float b10 = bias[2*FF + col], b11 = bias[3*FF + col];

    int base = blockIdx.x * 64;
    #pragma unroll
    for (int s = 0; s < 4; ++s) {
        int arow = base + s*16 + col16;
        if (arow >= NN) arow = NN - 1;
        const float* xp = x + arow*FF + kg*8;
        float4 v0 = *(const float4*)xp;
        float4 v1 = *(const float4*)(xp + 4);
        float4 v2 = *(const float4*)(xp + 32);
        float4 v3 = *(const float4*)(xp + 36);
        bf16x8 A0, A1;
        A0[0]=bf16_of(v0.x); A0[1]=bf16_of(v0.y); A0[2]=bf16_of(v0.z); A0[3]=bf16_of(v0.w);
        A0[4]=bf16_of(v1.x); A0[5]=bf16_of(v1.y); A0[6]=bf16_of(v1.z); A0[7]=bf16_of(v1.w);
        A1[0]=bf16_of(v2.x); A1[1]=bf16_of(v2.y); A1[2]=bf16_of(v2.z); A1[3]=bf16_of(v2.w);
        A1[4]=bf16_of(v3.x); A1[5]=bf16_of(v3.y); A1[6]=bf16_of(v3.z); A1[7]=bf16_of(v3.w);

        f32x4 hi0 = {0.f,0.f,0.f,0.f}, hi1 = {0.f,0.f,0.f,0.f};
        hi0 = __builtin_amdgcn_mfma_f32_16x16x32_bf16(A0, Bi[0][0], hi0, 0, 0, 0);
        hi0 = __builtin_amdgcn_mfma_f32_16x16x32_bf16(A1, Bi[0][1], hi0, 0, 0, 0);
        hi1 = __builtin_amdgcn_mfma_f32_16x16x32_bf16(A0, Bi[1][0], hi1, 0, 0, 0);
        hi1 = __builtin_amdgcn_mfma_f32_16x16x32_bf16(A1, Bi[1][1], hi1, 0, 0, 0);
        f32x4 r00 = {b00,b00,b00,b00}, r01 = {b01,b01,b01,b01};
        r00 = __builtin_amdgcn_mfma_f32_16x16x32_bf16(A0, B0[0][0], r00, 0, 0, 0);
        r00 = __builtin_amdgcn_mfma_f32_16x16x32_bf16(A1, B0[0][1], r00, 0, 0, 0);
        r01 = __builtin_amdgcn_mfma_f32_16x16x32_bf16(A0, B0[1][0], r01, 0, 0, 0);
        r01 = __builtin_amdgcn_mfma_f32_16x16x32_bf16(A1, B0[1][1], r01, 0, 0, 0);
        f32x4 r10 = {b10,b10,b10,b10}, r11 = {b11,b11,b11,b11};
        r10 = __builtin_amdgcn_mfma_f32_16x16x32_bf16(A0, B1[0][0], r10, 0, 0, 0);
        r10 = __builtin_amdgcn_mfma_f32_16x16x32_bf16(A1, B1[0][1], r10, 0, 0, 0);
        r11 = __builtin_amdgcn_mfma_f32_16x16x32_bf16(A0, B1[1][0], r11, 0, 0, 0);
        r11 = __builtin_amdgcn_mfma_f32_16x16x32_bf16(A1, B1[1][1], r11, 0, 0, 0);
        #pragma unroll
        for (int r = 0; r < 4; ++r) {
            int node = base + s*16 + kg*4 + r;
            if (node < NN) {
                float f = dsc[node];
                hbf8[(node<<6) + col]  = fp8x2_of(hi0[r]*f, hi1[r]*f);
                rbf0[(node<<6) + col] = pack_bf16x2(r00[r], r01[r]);
                rbf1[(node<<6) + col] = pack_bf16x2(r10[r], r11[r]);
            }
        }
    }
}

// ==== MFMA layer matmul: outp8 = fp8(in_k0@W[0], in_k1@W[1]) * dinv ====
__global__ __launch_bounds__(256) void k_mml(const unsigned* __restrict__ in,
                                             const float* __restrict__ W,
                                             const float* __restrict__ dsc,
                                             unsigned short* __restrict__ outp8) {
    int lane = threadIdx.x & 63, wid = threadIdx.x >> 6;
    int col16 = lane & 15, kg = lane >> 4;
    int col = wid*16 + col16;

    bf16x8 B0[2], B1[2];
    #pragma unroll
    for (int c = 0; c < 2; ++c) {
        B0[c] = load_bfrag(W, col, kg, c);
        B1[c] = load_bfrag(W + 4096, col, kg, c);
    }
    int base = blockIdx.x * 64;
    #pragma unroll
    for (int s = 0; s < 4; ++s) {
        int arow = base + s*16 + col16;
        if (arow >= NN) arow = NN - 1;
        const unsigned* ip = in + arow*FF + kg*8;
        uint4 u0 = *(const uint4*)ip;
        uint4 u1 = *(const uint4*)(ip + 4);
        uint4 u2 = *(const uint4*)(ip + 32);
        uint4 u3 = *(const uint4*)(ip + 36);
        unsigned uu[16] = {u0.x,u0.y,u0.z,u0.w, u1.x,u1.y,u1.z,u1.w,
                           u2.x,u2.y,u2.z,u2.w, u3.x,u3.y,u3.z,u3.w};
        bf16x8 A00, A01, A10, A11;
        #pragma unroll
        for (int i = 0; i < 8; ++i) {
            A00[i] = (short)(uu[i] & 0xFFFFu);      A10[i] = (short)(uu[i] >> 16);
            A01[i] = (short)(uu[8+i] & 0xFFFFu);    A11[i] = (short)(uu[8+i] >> 16);
        }
        f32x4 a0 = {0.f, 0.f, 0.f, 0.f};
        f32x4 a1 = {0.f, 0.f, 0.f, 0.f};
        a0 = __builtin_amdgcn_mfma_f32_16x16x32_bf16(A00, B0[0], a0, 0, 0, 0);
        a0 = __builtin_amdgcn_mfma_f32_16x16x32_bf16(A01, B0[1], a0, 0, 0, 0);
        a1 = __builtin_amdgcn_mfma_f32_16x16x32_bf16(A10, B1[0], a1, 0, 0, 0);
        a1 = __builtin_amdgcn_mfma_f32_16x16x32_bf16(A11, B1[1], a1, 0, 0, 0);
        #pragma unroll
        for (int r = 0; r < 4; ++r) {
            int node = base + s*16 + kg*4 + r;
            if (node < NN) {
                float f = dsc[node];
                outp8[(node<<6) + col] = fp8x2_of(a0[r]*f, a1[r]*f);
            }
        }
    }
}

// ==== pull: 2 nodes/wave, shared staging window, 8B edat, fp8 payload ====
__global__ __launch_bounds__(512) void k_pull(const int* __restrict__ off,
                                              const uint2* __restrict__ edat,
                                              const unsigned short* __restrict__ hbf,
                                              const unsigned* __restrict__ rbf,
                                              const float* __restrict__ dinv,
                                              unsigned* __restrict__ out_bf,
                                              float* __restrict__ out_f32,
                                              int final_mean) {
    __shared__ uint2 ech[8][64];
    int lane = threadIdx.x & 63;
    int sub = threadIdx.x >> 6;
    int n0 = (blockIdx.x * 8 + sub) * 2;   // grid 6250 * 8 waves * 2 nodes == NN
    if (n0 >= NN) return;
    int n1 = n0 + 1;

    int beg = off[n0], mid = off[n0+1], end = off[n0+2];
    float dc0 = dinv[n0], dc1 = dinv[n1];
    unsigned rv0 = rbf[(n0<<6) + lane];
    unsigned rv1 = rbf[(n1<<6) + lane];

    float pa0=0.f,pa1=0.f,pb0=0.f,pb1=0.f,pc0=0.f,pc1=0.f,pd0=0.f,pd1=0.f;
    float qa0=0.f,qa1=0.f,qb0=0.f,qb1=0.f,qc0=0.f,qc1=0.f,qd0=0.f,qd1=0.f;

    for (int base = beg; base < end; base += 64) {
        int rem = end - base;
        int cc = rem < 64 ? rem : 64;
        ech[sub][lane] = (lane < cc) ? edat[base + lane] : make_uint2(0u, 0u);
        __builtin_amdgcn_wave_barrier();
        int midrel = mid - base;
        if (midrel < 0) midrel = 0;
        if (midrel > 64) midrel = 64;
        int padded = (cc + 7) & ~7;
        for (int q = 0; q < padded; q += 8) {
            uint2 e[8];
            #pragma unroll
            for (int i = 0; i < 8; ++i) e[i] = ech[sub][q + i];
            unsigned us[8];
            #pragma unroll
            for (int i = 0; i < 8; ++i) us[i] = hbf[e[i].x + lane];
            if (q + 8 <= midrel) {
                #pragma unroll
                for (int i = 0; i < 8; ++i) {
                    float w = __uint_as_float(e[i].y);
                    f32x2 h = __builtin_amdgcn_cvt_pk_f32_fp8(us[i], false);
                    if      ((i & 3) == 0) { pa0 = fmaf(w, h.x, pa0); pa1 = fmaf(w, h.y, pa1); }
                    else if ((i & 3) == 1) { pb0 = fmaf(w, h.x, pb0); pb1 = fmaf(w, h.y, pb1); }
                    else if ((i & 3) == 2) { pc0 = fmaf(w, h.x, pc0); pc1 = fmaf(w, h.y, pc1); }
                    else                   { pd0 = fmaf(w, h.x, pd0); pd1 = fmaf(w, h.y, pd1); }
                }
            } else if (q >= midrel) {
                #pragma unroll
                for (int i = 0; i < 8; ++i) {
                    float w = __uint_as_float(e[i].y);
                    f32x2 h = __builtin_amdgcn_cvt_pk_f32_fp8(us[i], false);
                    if      ((i & 3) == 0) { qa0 = fmaf(w, h.x, qa0); qa1 = fmaf(w, h.y, qa1); }
                    else if ((i & 3) == 1) { qb0 = fmaf(w, h.x, qb0); qb1 = fmaf(w, h.y, qb1); }
                    else if ((i & 3) == 2) { qc0 = fmaf(w, h.x, qc0); qc1 = fmaf(w, h.y, qc1); }
                    else                   { qd0 = fmaf(w, h.x, qd0); qd1 = fmaf(w, h.y, qd1); }
                }
            } else {
                #pragma unroll
                for (int i = 0; i < 8; ++i) {
                    float w = __uint_as_float(e[i].y);
                    f32x2 h = __builtin_amdgcn_cvt_pk_f32_fp8(us[i], false);
                    if (q + i < midrel) {
                        if      ((i & 3) == 0) { pa0 = fmaf(w, h.x, pa0); pa1 = fmaf(w, h.y, pa1); }
                        else if ((i & 3) == 1) { pb0 = fmaf(w, h.x, pb0); pb1 = fmaf(w, h.y, pb1); }
                        else if ((i & 3) == 2) { pc0 = fmaf(w, h.x, pc0); pc1 = fmaf(w, h.y, pc1); }
                        else                   { pd0 = fmaf(w, h.x, pd0); pd1 = fmaf(w, h.y, pd1); }
                    } else {
                        if      ((i & 3) == 0) { qa0 = fmaf(w, h.x, qa0); qa1 = fmaf(w, h.y, qa1); }
                        else if ((i & 3) == 1) { qb0 = fmaf(w, h.x, qb0); qb1 = fmaf(w, h.y, qb1); }
                        else if ((i & 3) == 2) { qc0 = fmaf(w, h.x, qc0); qc1 = fmaf(w, h.y, qc1); }
                        else                   { qd0 = fmaf(w, h.x, qd0); qd1 = fmaf(w, h.y, qd1); }
                    }
                }
            }
        }
        __builtin_amdgcn_wave_barrier();
    }
    float s00 = fmaxf(fmaf(dc0, pa0 + pb0 + pc0 + pd0, bf_lo(rv0)), 0.f);
    float s01 = fmaxf(fmaf(dc0, pa1 + pb1 + pc1 + pd1, bf_hi(rv0)), 0.f);
    float s10 = fmaxf(fmaf(dc1, qa0 + qb0 + qc0 + qd0, bf_lo(rv1)), 0.f);
    float s11 = fmaxf(fmaf(dc1, qa1 + qb1 + qc1 + qd1, bf_hi(rv1)), 0.f);
    if (final_mean) {
        out_f32[n0*FF + lane] = 0.5f * (s00 + s01);
        out_f32[n1*FF + lane] = 0.5f * (s10 + s11);
    } else {
        out_bf[(n0<<6) + lane] = pack_bf16x2(s00, s01);
        out_bf[(n1<<6) + lane] = pack_bf16x2(s10, s11);
    }
}

extern "C" void kernel_launch(void* const* d_in, const int* in_sizes, int n_in,
                              void* d_out, int out_size, void* d_ws, size_t ws_size,
                              hipStream_t stream) {
    const float* x    = (const float*)d_in[0];
    const int*   ei   = (const int*)d_in[1];
    const float* ew   = (const float*)d_in[2];
    const float* iw   = (const float*)d_in[3];   // [K,64,64]
    const float* w    = (const float*)d_in[4];   // [T-1,K,64,64]
    const float* rw   = (const float*)d_in[5];   // [T,K,64,64]
    const float* bias = (const float*)d_in[6];   // [T,K,64]
    float* out = (float*)d_out;

    // workspace layout (~103 MB)
    uint2* records = (uint2*)d_ws;                        // NBKT*CAP*8B = 25.62 MB
    unsigned* rbf1 = (unsigned*)records;                  // aliases records (dead after p2)
    unsigned short* hbf8 = (unsigned short*)(records + (size_t)NBKT*CAP);  // NN*64*2B
    unsigned* gbf  = (unsigned*)(hbf8 + (NN<<6));         // NN*64*4B
    unsigned* rbf0 = gbf + (NN<<6);                       // NN*64*4B
    uint2* edat    = (uint2*)(rbf0 + (NN<<6));            // EE*8B = 12.8 MB
    float* dinv    = (float*)(edat + EE);                 // NN
    int*   off     = (int*)(dinv + NN);                   // NN+1
    int*   gcnt    = off + NN + 1;                        // NBKT

    const int* row = ei;        // edge_index[0]
    const int* col = ei + EE;   // edge_index[1]

    const int NB = (NN + 63) / 64;   // 1563 MFMA tiles

    // ---- CSR build ----
    hipMemsetAsync(gcnt, 0, NBKT * sizeof(int), stream);
    k_p1<<<256, 512, 0, stream>>>(row, col, ew, gcnt, records);
    k_p2<<<NBKT, 512, 0, stream>>>(gcnt, records, off, dinv, edat);

    // ---- projections (single x pass; rbf1 overwrites dead records) ----
    k_proj3<<<NB, 256, 0, stream>>>(x, iw, rw, bias, dinv, hbf8, rbf0, rbf1);

    // ---- t = 0 ----
    k_pull<<<6250, 512, 0, stream>>>(off, edat, hbf8, rbf0, dinv, gbf, out, 0);

    // ---- t = 1 ----
    k_mml<<<NB, 256, 0, stream>>>(gbf, w, dinv, hbf8);   // hbf8 = fp8((g@w0)*dinv)
    k_pull<<<6250, 512, 0, stream>>>(off, edat, hbf8, rbf1, dinv, gbf, out, 1);
}

// Round 16
// 184.363 us; speedup vs baseline: 1.2145x; 1.0298x over previous
//
#include <hip/hip_runtime.h>

#define NN 100000
#define EE 1600000
#define FF 64
#define KK 2

#define NBKT 391          // ceil(NN/256) coarse buckets (col>>8)
#define BKW 256           // nodes per bucket
#define CAP 8192          // record capacity per bucket
#define EPB 6250          // edges per pass-1 block (EE/256 exactly)
#define P2CAP 6144        // LDS staging capacity in pass 2 (48 KB)

#define FIX 68719476736.0f       // 2^36
#define FIXINV (1.0/68719476736.0)

typedef unsigned long long ull;
typedef __attribute__((ext_vector_type(8))) short bf16x8;   // 8 bf16 (4 VGPRs)
typedef __attribute__((ext_vector_type(4))) float f32x4;    // MFMA acc
typedef __attribute__((ext_vector_type(2))) float f32x2;

__device__ inline unsigned pack_bf16x2(float a, float b) {
    unsigned ua = __float_as_uint(a), ub = __float_as_uint(b);
    ua = (ua + 0x7FFFu + ((ua >> 16) & 1u)) >> 16;
    ub = (ub + 0x7FFFu + ((ub >> 16) & 1u)) >> 16;
    return ua | (ub << 16);
}
__device__ inline float bf_lo(unsigned u) { return __uint_as_float(u << 16); }
__device__ inline float bf_hi(unsigned u) { return __uint_as_float(u & 0xFFFF0000u); }
__device__ inline short bf16_of(float f) {
    unsigned u = __float_as_uint(f);
    u = (u + 0x7FFFu + ((u >> 16) & 1u)) >> 16;
    return (short)u;
}
__device__ inline unsigned bf16_bits(float f) {
    unsigned u = __float_as_uint(f);
    return (u + 0x7FFFu + ((u >> 16) & 1u)) >> 16;
}
// pack two f32 -> two fp8 e4m3 bytes (HW convert)
__device__ inline unsigned short fp8x2_of(float a, float b) {
    int p = __builtin_amdgcn_cvt_pk_fp8_f32(a, b, 0, false);
    return (unsigned short)(p & 0xFFFF);
}

// B-frag: lane holds W[c*32 + kg*8 + i][col], i=0..7 (K=32 chunk c)
__device__ inline bf16x8 load_bfrag(const float* __restrict__ W, int col, int kg, int c) {
    bf16x8 f;
    #pragma unroll
    for (int i = 0; i < 8; ++i)
        f[i] = bf16_of(W[(c*32 + kg*8 + i)*FF + col]);
    return f;
}

// ==== Pass 1: LDS counting sort by col>>8, coalesced run writes (512 thr) ====
__global__ __launch_bounds__(512) void k_p1(const int* __restrict__ row,
                                            const int* __restrict__ col,
                                            const float* __restrict__ ew,
                                            int* __restrict__ gcnt,
                                            uint2* __restrict__ records) {
    __shared__ uint2 srt[EPB];        // 50 KB sorted records
    __shared__ int colsS[EPB];        // 25 KB staged cols
    __shared__ int histo[NBKT];
    __shared__ int lbase[NBKT];
    __shared__ int gbase[NBKT];
    __shared__ int cur[NBKT];
    __shared__ int tmp[512];
    int tid = threadIdx.x;
    for (int i = tid; i < NBKT; i += 512) histo[i] = 0;
    __syncthreads();
    int s0 = blockIdx.x * EPB;
    #pragma unroll 1
    for (int r = 0; r < 13; ++r) {
        int t = r*512 + tid;
        if (t < EPB) {
            int c = col[s0 + t];
            colsS[t] = c;
            atomicAdd(&histo[c >> 8], 1);
        }
    }
    __syncthreads();
    int v = (tid < NBKT) ? histo[tid] : 0;
    tmp[tid] = v;
    __syncthreads();
    #pragma unroll
    for (int s = 1; s < 512; s <<= 1) {
        int t = (tid >= s) ? tmp[tid - s] : 0;
        __syncthreads();
        tmp[tid] += t;
        __syncthreads();
    }
    if (tid < NBKT) {
        int ex = tmp[tid] - v;
        lbase[tid] = ex;
        cur[tid] = ex;
        gbase[tid] = atomicAdd(&gcnt[tid], v);
    }
    __syncthreads();
    #pragma unroll 1
    for (int r = 0; r < 13; ++r) {
        int t = r*512 + tid;
        if (t < EPB) {
            int i = s0 + t;
            int c = colsS[t];
            int b = c >> 8;
            int slot = atomicAdd(&cur[b], 1);
            srt[slot] = make_uint2(((unsigned)row[i] << 8) | (unsigned)(c & 255),
                                   __float_as_uint(ew[i]));
        }
    }
    __syncthreads();
    int wid = tid >> 6, lane = tid & 63;
    for (int b = wid; b < NBKT; b += 8) {
        int n = histo[b], lb = lbase[b];
        size_t gb = (size_t)b*CAP + gbase[b];
        for (int i = lane; i < n; i += 64) records[gb + i] = srt[lb + i];
    }
}

// ==== Pass 2: u64 LDS hist+deg, scan, ranked 4B-edat write (512 thr) ====
__global__ __launch_bounds__(512) void k_p2(const int* __restrict__ gcnt,
                                            const uint2* __restrict__ records,
                                            int* __restrict__ off,
                                            float* __restrict__ dinv,
                                            unsigned* __restrict__ edat) {
    __shared__ uint2 rstage[P2CAP];   // 48 KB
    __shared__ ull hd[BKW];           // [cnt:16 | deg Q36:48]
    __shared__ int loff[BKW];
    __shared__ int cur[BKW];
    __shared__ int tmp[512];
    int tid = threadIdx.x;
    int b = blockIdx.x;
    int cnt = gcnt[b];
    // fused exclusive scan of bucket totals -> obase
    int v = (tid < NBKT) ? gcnt[tid] : 0;
    tmp[tid] = v;
    __syncthreads();
    #pragma unroll
    for (int s = 1; s < 512; s <<= 1) {
        int t = (tid >= s) ? tmp[tid - s] : 0;
        __syncthreads();
        tmp[tid] += t;
        __syncthreads();
    }
    int obase = tmp[b] - cnt;
    if (b == 0 && tid == 0) off[NN] = EE;
    if (tid < BKW) hd[tid] = 0ull;
    __syncthreads();
    size_t rbase = (size_t)b * CAP;
    for (int j = tid; j < cnt; j += 512) {
        uint2 rec = records[rbase + j];
        if (j < P2CAP) rstage[j] = rec;
        int c8 = rec.x & 255;
        atomicAdd(&hd[c8], (1ull << 48) | (ull)(__uint_as_float(rec.y) * FIX));
    }
    __syncthreads();
    int hv = (tid < BKW) ? (int)(hd[tid] >> 48) : 0;
    tmp[tid] = hv;
    __syncthreads();
    #pragma unroll
    for (int s = 1; s < 512; s <<= 1) {
        int t = (tid >= s) ? tmp[tid - s] : 0;
        __syncthreads();
        tmp[tid] += t;
        __syncthreads();
    }
    if (tid < BKW) {
        int excl = tmp[tid] - hv;
        loff[tid] = excl;
        cur[tid] = excl;
        int node = b*BKW + tid;
        if (node < NN) {
            off[node] = obase + excl;
            float d = (float)((double)(hd[tid] & 0xFFFFFFFFFFFFull) * FIXINV);
            dinv[node] = d > 0.f ? rsqrtf(fmaxf(d, 1e-12f)) : 0.f;
        }
    }
    __syncthreads();
    for (int j = tid; j < cnt; j += 512) {
        uint2 rec = (j < P2CAP) ? rstage[j] : records[rbase + j];
        int c8 = rec.x & 255;
        int slot = atomicAdd(&cur[c8], 1);
        edat[obase + slot] = ((rec.x >> 8) << 15) |
                             (bf16_bits(__uint_as_float(rec.y)) & 0x7FFFu);
    }
}

// ==== MFMA triple projection (one x pass): hbf8 (fp8), rbf0, rbf1 (bf16) ====
__global__ __launch_bounds__(256) void k_proj3(const float* __restrict__ x,
                                               const float* __restrict__ iw,
                                               const float* __restrict__ rw,
                                               const float* __restrict__ bias,
                                               const float* __restrict__ dsc,
                                               unsigned short* __restrict__ hbf8,
                                               unsigned* __restrict__ rbf0,
                                               unsigned* __restrict__ rbf1) {
    int lane = threadIdx.x & 63, wid = threadIdx.x >> 6;
    int col16 = lane & 15, kg = lane >> 4;
    int col = wid*16 + col16;

    bf16x8 Bi[2][2], B0[2][2], B1[2][2];   // [k][chunk]
    #pragma unroll
    for (int k = 0; k < 2; ++k)
        #pragma unroll
        for (int c = 0; c < 2; ++c) {
            Bi[k][c] = load_bfrag(iw + k*4096, col, kg, c);
            B0[k][c] = load_bfrag(rw + k*4096, col, kg, c);
            B1[k][c] = load_bfrag(rw + (2 + k)*4096, col, kg, c);
        }
    float b00 = bias[col],        b01 = bias[FF + col];
    float b10 = bias[2*FF + col], b11 = bias[3*FF + col];

    int base = blockIdx.x * 64;
    #pragma unroll
    for (int s = 0; s < 4; ++s) {
        int arow = base + s*16 + col16;
        if (arow >= NN) arow = NN - 1;
        const float* xp = x + arow*FF + kg*8;
        float4 v0 = *(const float4*)xp;
        float4 v1 = *(const float4*)(xp + 4);
        float4 v2 = *(const float4*)(xp + 32);
        float4 v3 = *(const float4*)(xp + 36);
        bf16x8 A0, A1;
        A0[0]=bf16_of(v0.x); A0[1]=bf16_of(v0.y); A0[2]=bf16_of(v0.z); A0[3]=bf16_of(v0.w);
        A0[4]=bf16_of(v1.x); A0[5]=bf16_of(v1.y); A0[6]=bf16_of(v1.z); A0[7]=bf16_of(v1.w);
        A1[0]=bf16_of(v2.x); A1[1]=bf16_of(v2.y); A1[2]=bf16_of(v2.z); A1[3]=bf16_of(v2.w);
        A1[4]=bf16_of(v3.x); A1[5]=bf16_of(v3.y); A1[6]=bf16_of(v3.z); A1[7]=bf16_of(v3.w);

        f32x4 hi0 = {0.f,0.f,0.f,0.f}, hi1 = {0.f,0.f,0.f,0.f};
        hi0 = __builtin_amdgcn_mfma_f32_16x16x32_bf16(A0, Bi[0][0], hi0, 0, 0, 0);
        hi0 = __builtin_amdgcn_mfma_f32_16x16x32_bf16(A1, Bi[0][1], hi0, 0, 0, 0);
        hi1 = __builtin_amdgcn_mfma_f32_16x16x32_bf16(A0, Bi[1][0], hi1, 0, 0, 0);
        hi1 = __builtin_amdgcn_mfma_f32_16x16x32_bf16(A1, Bi[1][1], hi1, 0, 0, 0);
        f32x4 r00 = {b00,b00,b00,b00}, r01 = {b01,b01,b01,b01};
        r00 = __builtin_amdgcn_mfma_f32_16x16x32_bf16(A0, B0[0][0], r00, 0, 0, 0);
        r00 = __builtin_amdgcn_mfma_f32_16x16x32_bf16(A1, B0[0][1], r00, 0, 0, 0);
        r01 = __builtin_amdgcn_mfma_f32_16x16x32_bf16(A0, B0[1][0], r01, 0, 0, 0);
        r01 = __builtin_amdgcn_mfma_f32_16x16x32_bf16(A1, B0[1][1], r01, 0, 0, 0);
        f32x4 r10 = {b10,b10,b10,b10}, r11 = {b11,b11,b11,b11};
        r10 = __builtin_amdgcn_mfma_f32_16x16x32_bf16(A0, B1[0][0], r10, 0, 0, 0);
        r10 = __builtin_amdgcn_mfma_f32_16x16x32_bf16(A1, B1[0][1], r10, 0, 0, 0);
        r11 = __builtin_amdgcn_mfma_f32_16x16x32_bf16(A0, B1[1][0], r11, 0, 0, 0);
        r11 = __builtin_amdgcn_mfma_f32_16x16x32_bf16(A1, B1[1][1], r11, 0, 0, 0);
        #pragma unroll
        for (int r = 0; r < 4; ++r) {
            int node = base + s*16 + kg*4 + r;
            if (node < NN) {
                float f = dsc[node];
                hbf8[(node<<6) + col]  = fp8x2_of(hi0[r]*f, hi1[r]*f);
                rbf0[(node<<6) + col] = pack_bf16x2(r00[r], r01[r]);
                rbf1[(node<<6) + col] = pack_bf16x2(r10[r], r11[r]);
            }
        }
    }
}

// ==== MFMA layer matmul: outp8 = fp8(in_k0@W[0], in_k1@W[1]) * dinv ====
__global__ __launch_bounds__(256) void k_mml(const unsigned* __restrict__ in,
                                             const float* __restrict__ W,
                                             const float* __restrict__ dsc,
                                             unsigned short* __restrict__ outp8) {
    int lane = threadIdx.x & 63, wid = threadIdx.x >> 6;
    int col16 = lane & 15, kg = lane >> 4;
    int col = wid*16 + col16;

    bf16x8 B0[2], B1[2];
    #pragma unroll
    for (int c = 0; c < 2; ++c) {
        B0[c] = load_bfrag(W, col, kg, c);
        B1[c] = load_bfrag(W + 4096, col, kg, c);
    }
    int base = blockIdx.x * 64;
    #pragma unroll
    for (int s = 0; s < 4; ++s) {
        int arow = base + s*16 + col16;
        if (arow >= NN) arow = NN - 1;
        const unsigned* ip = in + arow*FF + kg*8;
        uint4 u0 = *(const uint4*)ip;
        uint4 u1 = *(const uint4*)(ip + 4);
        uint4 u2 = *(const uint4*)(ip + 32);
        uint4 u3 = *(const uint4*)(ip + 36);
        unsigned uu[16] = {u0.x,u0.y,u0.z,u0.w, u1.x,u1.y,u1.z,u1.w,
                           u2.x,u2.y,u2.z,u2.w, u3.x,u3.y,u3.z,u3.w};
        bf16x8 A00, A01, A10, A11;
        #pragma unroll
        for (int i = 0; i < 8; ++i) {
            A00[i] = (short)(uu[i] & 0xFFFFu);      A10[i] = (short)(uu[i] >> 16);
            A01[i] = (short)(uu[8+i] & 0xFFFFu);    A11[i] = (short)(uu[8+i] >> 16);
        }
        f32x4 a0 = {0.f, 0.f, 0.f, 0.f};
        f32x4 a1 = {0.f, 0.f, 0.f, 0.f};
        a0 = __builtin_amdgcn_mfma_f32_16x16x32_bf16(A00, B0[0], a0, 0, 0, 0);
        a0 = __builtin_amdgcn_mfma_f32_16x16x32_bf16(A01, B0[1], a0, 0, 0, 0);
        a1 = __builtin_amdgcn_mfma_f32_16x16x32_bf16(A10, B1[0], a1, 0, 0, 0);
        a1 = __builtin_amdgcn_mfma_f32_16x16x32_bf16(A11, B1[1], a1, 0, 0, 0);
        #pragma unroll
        for (int r = 0; r < 4; ++r) {
            int node = base + s*16 + kg*4 + r;
            if (node < NN) {
                float f = dsc[node];
                outp8[(node<<6) + col] = fp8x2_of(a0[r]*f, a1[r]*f);
            }
        }
    }
}

// ==== pull: 2 nodes/wave, shared staging window, 4B edat, fp8 gather ====
__global__ __launch_bounds__(512) void k_pull(const int* __restrict__ off,
                                              const unsigned* __restrict__ edat,
                                              const unsigned short* __restrict__ hbf,
                                              const unsigned* __restrict__ rbf,
                                              const float* __restrict__ dinv,
                                              unsigned* __restrict__ out_bf,
                                              float* __restrict__ out_f32,
                                              int final_mean) {
    __shared__ unsigned ech[8][64];
    int lane = threadIdx.x & 63;
    int sub = threadIdx.x >> 6;
    int n0 = (blockIdx.x * 8 + sub) * 2;   // grid 6250 * 8 waves * 2 nodes == NN
    if (n0 >= NN) return;
    int n1 = n0 + 1;

    int beg = off[n0], mid = off[n0+1], end = off[n0+2];
    float dc0 = dinv[n0], dc1 = dinv[n1];
    unsigned rv0 = rbf[(n0<<6) + lane];
    unsigned rv1 = rbf[(n1<<6) + lane];

    float pa0=0.f,pa1=0.f,pb0=0.f,pb1=0.f,pc0=0.f,pc1=0.f,pd0=0.f,pd1=0.f;
    float qa0=0.f,qa1=0.f,qb0=0.f,qb1=0.f,qc0=0.f,qc1=0.f,qd0=0.f,qd1=0.f;

    for (int base = beg; base < end; base += 64) {
        int rem = end - base;
        int cc = rem < 64 ? rem : 64;
        ech[sub][lane] = (lane < cc) ? edat[base + lane] : 0u;
        __builtin_amdgcn_wave_barrier();
        int midrel = mid - base;
        if (midrel < 0) midrel = 0;
        if (midrel > 64) midrel = 64;
        int padded = (cc + 7) & ~7;
        for (int q = 0; q < padded; q += 8) {
            unsigned e[8];
            #pragma unroll
            for (int i = 0; i < 8; ++i) e[i] = ech[sub][q + i];
            unsigned us[8];
            #pragma unroll
            for (int i = 0; i < 8; ++i)
                us[i] = hbf[((e[i] >> 15) << 6) + lane];
            if (q + 8 <= midrel) {
                #pragma unroll
                for (int i = 0; i < 8; ++i) {
                    float w = __uint_as_float((e[i] & 0x7FFFu) << 16);
                    f32x2 h = __builtin_amdgcn_cvt_pk_f32_fp8(us[i], false);
                    if      ((i & 3) == 0) { pa0 = fmaf(w, h.x, pa0); pa1 = fmaf(w, h.y, pa1); }
                    else if ((i & 3) == 1) { pb0 = fmaf(w, h.x, pb0); pb1 = fmaf(w, h.y, pb1); }
                    else if ((i & 3) == 2) { pc0 = fmaf(w, h.x, pc0); pc1 = fmaf(w, h.y, pc1); }
                    else                   { pd0 = fmaf(w, h.x, pd0); pd1 = fmaf(w, h.y, pd1); }
                }
            } else if (q >= midrel) {
                #pragma unroll
                for (int i = 0; i < 8; ++i) {
                    float w = __uint_as_float((e[i] & 0x7FFFu) << 16);
                    f32x2 h = __builtin_amdgcn_cvt_pk_f32_fp8(us[i], false);
                    if      ((i & 3) == 0) { qa0 = fmaf(w, h.x, qa0); qa1 = fmaf(w, h.y, qa1); }
                    else if ((i & 3) == 1) { qb0 = fmaf(w, h.x, qb0); qb1 = fmaf(w, h.y, qb1); }
                    else if ((i & 3) == 2) { qc0 = fmaf(w, h.x, qc0); qc1 = fmaf(w, h.y, qc1); }
                    else                   { qd0 = fmaf(w, h.x, qd0); qd1 = fmaf(w, h.y, qd1); }
                }
            } else {
                #pragma unroll
                for (int i = 0; i < 8; ++i) {
                    float w = __uint_as_float((e[i] & 0x7FFFu) << 16);
                    f32x2 h = __builtin_amdgcn_cvt_pk_f32_fp8(us[i], false);
                    if (q + i < midrel) {
                        if      ((i & 3) == 0) { pa0 = fmaf(w, h.x, pa0); pa1 = fmaf(w, h.y, pa1); }
                        else if ((i & 3) == 1) { pb0 = fmaf(w, h.x, pb0); pb1 = fmaf(w, h.y, pb1); }
                        else if ((i & 3) == 2) { pc0 = fmaf(w, h.x, pc0); pc1 = fmaf(w, h.y, pc1); }
                        else                   { pd0 = fmaf(w, h.x, pd0); pd1 = fmaf(w, h.y, pd1); }
                    } else {
                        if      ((i & 3) == 0) { qa0 = fmaf(w, h.x, qa0); qa1 = fmaf(w, h.y, qa1); }
                        else if ((i & 3) == 1) { qb0 = fmaf(w, h.x, qb0); qb1 = fmaf(w, h.y, qb1); }
                        else if ((i & 3) == 2) { qc0 = fmaf(w, h.x, qc0); qc1 = fmaf(w, h.y, qc1); }
                        else                   { qd0 = fmaf(w, h.x, qd0); qd1 = fmaf(w, h.y, qd1); }
                    }
                }
            }
        }
        __builtin_amdgcn_wave_barrier();
    }
    float s00 = fmaxf(fmaf(dc0, pa0 + pb0 + pc0 + pd0, bf_lo(rv0)), 0.f);
    float s01 = fmaxf(fmaf(dc0, pa1 + pb1 + pc1 + pd1, bf_hi(rv0)), 0.f);
    float s10 = fmaxf(fmaf(dc1, qa0 + qb0 + qc0 + qd0, bf_lo(rv1)), 0.f);
    float s11 = fmaxf(fmaf(dc1, qa1 + qb1 + qc1 + qd1, bf_hi(rv1)), 0.f);
    if (final_mean) {
        out_f32[n0*FF + lane] = 0.5f * (s00 + s01);
        out_f32[n1*FF + lane] = 0.5f * (s10 + s11);
    } else {
        out_bf[(n0<<6) + lane] = pack_bf16x2(s00, s01);
        out_bf[(n1<<6) + lane] = pack_bf16x2(s10, s11);
    }
}

extern "C" void kernel_launch(void* const* d_in, const int* in_sizes, int n_in,
                              void* d_out, int out_size, void* d_ws, size_t ws_size,
                              hipStream_t stream) {
    const float* x    = (const float*)d_in[0];
    const int*   ei   = (const int*)d_in[1];
    const float* ew   = (const float*)d_in[2];
    const float* iw   = (const float*)d_in[3];   // [K,64,64]
    const float* w    = (const float*)d_in[4];   // [T-1,K,64,64]
    const float* rw   = (const float*)d_in[5];   // [T,K,64,64]
    const float* bias = (const float*)d_in[6];   // [T,K,64]
    float* out = (float*)d_out;

    // workspace layout (~97 MB)
    uint2* records = (uint2*)d_ws;                        // NBKT*CAP*8B = 25.62 MB
    unsigned* rbf1 = (unsigned*)records;                  // aliases records (dead after p2)
    unsigned short* hbf8 = (unsigned short*)(records + (size_t)NBKT*CAP);  // NN*64*2B
    unsigned* gbf  = (unsigned*)(hbf8 + (NN<<6));         // NN*64*4B
    unsigned* rbf0 = gbf + (NN<<6);                       // NN*64*4B
    unsigned* edat = rbf0 + (NN<<6);                      // EE*4B = 6.4 MB
    float* dinv    = (float*)(edat + EE);                 // NN
    int*   off     = (int*)(dinv + NN);                   // NN+1
    int*   gcnt    = off + NN + 1;                        // NBKT

    const int* row = ei;        // edge_index[0]
    const int* col = ei + EE;   // edge_index[1]

    const int NB = (NN + 63) / 64;   // 1563 MFMA tiles

    // ---- CSR build ----
    hipMemsetAsync(gcnt, 0, NBKT * sizeof(int), stream);
    k_p1<<<256, 512, 0, stream>>>(row, col, ew, gcnt, records);
    k_p2<<<NBKT, 512, 0, stream>>>(gcnt, records, off, dinv, edat);

    // ---- projections (single x pass; rbf1 overwrites dead records) ----
    k_proj3<<<NB, 256, 0, stream>>>(x, iw, rw, bias, dinv, hbf8, rbf0, rbf1);

    // ---- t = 0 ----
    k_pull<<<6250, 512, 0, stream>>>(off, edat, hbf8, rbf0, dinv, gbf, out, 0);

    // ---- t = 1 ----
    k_mml<<<NB, 256, 0, stream>>>(gbf, w, dinv, hbf8);   // hbf8 = fp8((g@w0)*dinv)
    k_pull<<<6250, 512, 0, stream>>>(off, edat, hbf8, rbf1, dinv, gbf, out, 1);
}